// Round 17
// baseline (202.934 us; speedup 1.0000x reference)
//
#include <hip/hip_runtime.h>
#include <cstdint>

typedef unsigned short u16;
typedef __attribute__((ext_vector_type(8))) __bf16 bf16x8;
typedef __attribute__((ext_vector_type(4))) float f32x4;
typedef __attribute__((ext_vector_type(16))) float f32x16;
typedef __attribute__((ext_vector_type(8))) unsigned short u16x8;

#define DEV __device__ __forceinline__

DEV u16 f2bf(float f) {
  __bf16 b = (__bf16)f;
  return __builtin_bit_cast(u16, b);
}
DEV float bf2f(u16 h) { return __uint_as_float(((unsigned)h) << 16); }
DEV float exp2_fast(float x) { float r; asm("v_exp_f32 %0, %1" : "=v"(r) : "v"(x)); return r; }
DEV void barrier_mem() { asm volatile("s_barrier" ::: "memory"); }

typedef __attribute__((address_space(1))) void gvoid_t;
typedef __attribute__((address_space(3))) void lvoid_t;

DEV void gload_lds16(const void* g, void* l) {
  __builtin_amdgcn_global_load_lds((gvoid_t*)(void*)(uintptr_t)g,
                                   (lvoid_t*)l, 16, 0, 0);
}

// ---- problem sizes
#define B_   2
#define T_   2048
#define DM   2048
#define MROWS (B_*T_)   // 4096
#define QSC  0.1275174f  // 128^-0.5 * log2(e): both attention mult factors + exp2 domain
#define PROW 72          // P strip row stride in u16 (144B: rotates bank base 4/row)

// ---------- fused prep: x->bf16 convert + 4 weight transposes + rope table ----------
__global__ void k_prep(const float* __restrict__ x,
                       const float* __restrict__ wq, const float* __restrict__ wk,
                       const float* __restrict__ wv, const float* __restrict__ wo,
                       u16* __restrict__ xb, u16* __restrict__ wqkvt,
                       u16* __restrict__ wot, float2* __restrict__ rope) {
  const int bid = blockIdx.x;
  const int tid = threadIdx.x;
  if (bid < 8192) {                        // x f32 -> bf16 (float4 per thread)
    int i = bid * 256 + tid;
    float4 v = ((const float4*)x)[i];
    ((ushort4*)xb)[i] = make_ushort4(f2bf(v.x), f2bf(v.y), f2bf(v.z), f2bf(v.w));
    return;
  }
  if (bid >= 18432) {                      // rope table [t][64] (cos, sin)
    int i = (bid - 18432) * 256 + tid;
    int pos = i >> 6, d = i & 63;
    float ang = powf(10000.0f, -(float)d / 64.0f);
    float s, c;
    sincosf((float)pos * ang, &s, &c);
    rope[i] = make_float2(c, s);
    return;
  }
  __shared__ float tile[32][33];
  const int tb = bid - 8192;
  const float* in;
  u16* out;
  int C, bx, by, crow0;
  if (tb < 4096)      { in = wq; out = wqkvt; C = 2048; bx = tb & 63;          by = tb >> 6;          crow0 = 0; }
  else if (tb < 5120) { in = wk; out = wqkvt; C = 512;  bx = (tb - 4096) & 15; by = (tb - 4096) >> 4; crow0 = 2048; }
  else if (tb < 6144) { in = wv; out = wqkvt; C = 512;  bx = (tb - 5120) & 15; by = (tb - 5120) >> 4; crow0 = 2560; }
  else                { in = wo; out = wot;   C = 2048; bx = (tb - 6144) & 63; by = (tb - 6144) >> 6; crow0 = 0; }
  const int c0 = bx * 32, r0 = by * 32;
  const int tx = tid & 31, ty = tid >> 5;   // (32, 8)
  #pragma unroll
  for (int j = 0; j < 32; j += 8)
    tile[ty + j][tx] = in[(size_t)(r0 + ty + j) * C + c0 + tx];
  __syncthreads();
  #pragma unroll
  for (int j = 0; j < 32; j += 8)
    out[(size_t)(crow0 + c0 + ty + j) * 2048 + r0 + tx] = f2bf(tile[tx][ty + j]);
}

// ---------- bf16 GEMM: C[M][N] = A[M][K] * BT[N][K]^T ----------
// 128^2 tile, XCD swizzle; v_mfma_f32_32x32x16_bf16 inner (verified in r14).
template <typename OutT>
__global__ __launch_bounds__(256) void k_gemm(
    const u16* __restrict__ A, const u16* __restrict__ BT, OutT* __restrict__ C,
    int M, int N, int K) {
  __shared__ u16 As[128 * 64];
  __shared__ u16 Bs[128 * 64];
  const int tid = threadIdx.x;
  const int w = tid >> 6, lane = tid & 63;
  const int lr32 = lane & 31, l5 = lane >> 5;
  const int nx = gridDim.x;
  const int flat = blockIdx.y * nx + blockIdx.x;
  const int cpx = (nx * gridDim.y) >> 3;
  const int f = (flat & 7) * cpx + (flat >> 3);
  const int m0 = (f / nx) * 128, n0 = (f % nx) * 128;
  const int wr = w >> 1, wc = w & 1;
  f32x16 acc[2][2] = {};
  for (int k0 = 0; k0 < K; k0 += 64) {
    __syncthreads();
    #pragma unroll
    for (int i = 0; i < 4; i++) {
      int idx = i * 256 + tid;            // 0..1023
      int row = idx >> 3, blk = idx & 7;  // 8x16B blocks per 128B row
      int scol = ((blk ^ (row & 7)) << 3);
      gload_lds16(&A[(size_t)(m0 + row) * K + k0 + scol], &As[(idx & ~63) * 8]);
      gload_lds16(&BT[(size_t)(n0 + row) * K + k0 + scol], &Bs[(idx & ~63) * 8]);
    }
    __syncthreads();
    #pragma unroll
    for (int kc = 0; kc < 4; kc++) {      // K chunks of 16
      bf16x8 af[2], bfr[2];
      #pragma unroll
      for (int m = 0; m < 2; m++) {
        int row = wr * 64 + m * 32 + lr32;
        int blk = (kc * 2 + l5) ^ (row & 7);
        af[m] = *(const bf16x8*)&As[row * 64 + (blk << 3)];
      }
      #pragma unroll
      for (int n = 0; n < 2; n++) {
        int row = wc * 64 + n * 32 + lr32;
        int blk = (kc * 2 + l5) ^ (row & 7);
        bfr[n] = *(const bf16x8*)&Bs[row * 64 + (blk << 3)];
      }
      #pragma unroll
      for (int m = 0; m < 2; m++)
        #pragma unroll
        for (int n = 0; n < 2; n++)
          acc[m][n] = __builtin_amdgcn_mfma_f32_32x32x16_bf16(af[m], bfr[n], acc[m][n], 0, 0, 0);
    }
  }
  #pragma unroll
  for (int m = 0; m < 2; m++)
    #pragma unroll
    for (int n = 0; n < 2; n++)
      #pragma unroll
      for (int reg = 0; reg < 16; reg++) {
        int row = m0 + wr * 64 + m * 32 + (reg & 3) + 8 * (reg >> 2) + 4 * l5;
        int col = n0 + wc * 64 + n * 32 + lr32;
        if constexpr (sizeof(OutT) == 2) C[(size_t)row * N + col] = f2bf(acc[m][n][reg]);
        else                             C[(size_t)row * N + col] = acc[m][n][reg];
      }
}

// ---------- fused post-GEMM: K norm+rope ([0,4096) blocks) + V transpose pack ----------
__global__ void k_postgemm(const u16* __restrict__ qkvf, const float* __restrict__ gk,
                           const float2* __restrict__ tab, u16* __restrict__ kb,
                           u16* __restrict__ vt) {
  const int bid = blockIdx.x;
  const int w = threadIdx.x >> 6, lane = threadIdx.x & 63;
  if (bid < 4096) {                       // K: RMSNorm * gk, RoPE -> [b,g,t,d]
    int W = bid * 4 + w;                  // 0..16383
    int g = W & 3;
    int bt = W >> 2;
    int t = bt & 2047, b = bt >> 11;
    const u16* row = qkvf + (size_t)bt * 3072 + 2048 + (size_t)g * 128;
    float v0 = bf2f(row[lane]);
    float v1 = bf2f(row[lane + 64]);
    float ss = v0 * v0 + v1 * v1;
    #pragma unroll
    for (int off = 1; off < 64; off <<= 1) ss += __shfl_xor(ss, off, 64);
    float inv = 1.0f / sqrtf(ss * (1.0f / 128.0f) + 1e-6f);
    v0 *= inv * gk[g * 128 + lane];
    v1 *= inv * gk[g * 128 + 64 + lane];
    float2 cs = tab[t * 64 + lane];
    float o0 = v0 * cs.x - v1 * cs.y;
    float o1 = v0 * cs.y + v1 * cs.x;
    u16* orow = kb + ((size_t)((b * 4 + g) * 2048 + t)) * 128;
    orow[lane] = f2bf(o0);
    orow[lane + 64] = f2bf(o1);
  } else {                                // V: cols 2560..3071 -> VT [b,g,d,t]
    int W = (bid - 4096) * 4 + w;         // 0..4095
    int t8 = W & 255, dh = (W >> 8) & 1, bg = W >> 9;
    int b = bg >> 2, g = bg & 3;
    int t0 = t8 * 8;
    int d = dh * 64 + lane;
    u16x8 pack;
    #pragma unroll
    for (int j = 0; j < 8; j++)
      pack[j] = qkvf[(size_t)(b * 2048 + t0 + j) * 3072 + 2560 + g * 128 + d];
    *(u16x8*)&vt[((size_t)(bg * 128 + d)) * 2048 + t0] = pack;
  }
}

// ---------- staging: K tile [64][128] + VT tile [128][64], pre-swizzled source ----------
// Exactly 8 VMEM instructions per wave (4 K + 4 V) -> vmcnt(8) = previous stage complete.
DEV void stage_tiles(const u16* kh, const u16* vh, int j0, u16* Kbuf, u16* Vbuf, int tid) {
  #pragma unroll
  for (int i = 0; i < 4; i++) {
    int idx = i * 256 + tid;
    int row = idx >> 4, blk = idx & 15;   // 16x16B blocks per 256B K row
    gload_lds16(&kh[(size_t)(j0 + row) * 128 + ((blk ^ (row & 7)) << 3)],
                &Kbuf[(idx & ~63) * 8]);
  }
  #pragma unroll
  for (int i = 0; i < 4; i++) {
    int idx = i * 256 + tid;
    int row = idx >> 3, blk = idx & 7;    // 8x16B blocks per 128B VT row
    gload_lds16(&vh[(size_t)row * T_ + j0 + ((blk ^ (row & 7)) << 3)],
                &Vbuf[(idx & ~63) * 8]);
  }
}

// ---------- one q-tile's QK^T + bias-free exp2 softmax + PV ----------
// P = exp2(s) raw: s <= 16.32 (RMS-normed q,k; D^-0.5*log2e folded into q) -> P <= 8.2e4.
// P strip rows padded to 144B (PROW=72 u16): row bank-base rotates 4/row, breaking the
// 4-lane 8B-block aliasing of the old 128B-stride layout (GEMM shows 0 conflicts with
// the same K/V frag patterns -> the P round-trip was the conflict source).
DEV void attn_tile(const u16* __restrict__ Kc, const u16* __restrict__ Vc,
                   u16* __restrict__ Psw, const bf16x8* qf, f32x4* oacc,
                   float& lsum, int lr, int lg, int w, bool diag) {
  // S^T = K . Q^T : col = q (lr), row = kv (c*16 + lg*4 + r)
  f32x4 s[4] = {};
  __builtin_amdgcn_s_setprio(1);
  #pragma unroll
  for (int kk = 0; kk < 4; kk++) {
    #pragma unroll
    for (int c = 0; c < 4; c++) {
      const int kvr = c * 16 + lr;
      bf16x8 kf = *(const bf16x8*)&Kc[kvr * 128 + (((kk * 4 + lg) ^ (kvr & 7)) << 3)];
      s[c] = __builtin_amdgcn_mfma_f32_16x16x32_bf16(kf, qf[kk], s[c], 0, 0, 0);
    }
  }
  __builtin_amdgcn_s_setprio(0);
  if (diag) {
    #pragma unroll
    for (int c = 0; c < 4; c++)
      #pragma unroll
      for (int r = 0; r < 4; r++)
        if (c * 16 + lg * 4 + r > w * 16 + lr) s[c][r] = -1.0e30f;
  }
  float rs = 0.f;
  #pragma unroll
  for (int c = 0; c < 4; c++)
    #pragma unroll
    for (int r = 0; r < 4; r++) {
      float pv = exp2_fast(s[c][r]);
      s[c][r] = pv;
      rs += pv;
    }
  lsum += rs;                 // per-lane partial; cross-lane reduce deferred to epilogue
  // P store: P[q=lr][kv quad c*16+lg*4], b64, XOR-swizzled 8B blocks, padded rows
  #pragma unroll
  for (int c = 0; c < 4; c++) {
    ushort4 q4 = make_ushort4(f2bf(s[c][0]), f2bf(s[c][1]), f2bf(s[c][2]), f2bf(s[c][3]));
    int blk8 = (c * 4 + lg) ^ ((lr & 7) << 1);
    *(ushort4*)&Psw[lr * PROW + blk8 * 4] = q4;
  }
  // O += P V
  #pragma unroll
  for (int ks = 0; ks < 2; ks++) {
    bf16x8 pf = *(const bf16x8*)&Psw[lr * PROW +
                 (((2 * (ks * 4 + lg)) ^ ((lr & 7) << 1)) << 2)];
    __builtin_amdgcn_s_setprio(1);
    #pragma unroll
    for (int nd = 0; nd < 8; nd++) {
      const int d = nd * 16 + lr;
      bf16x8 vf = *(const bf16x8*)&Vc[d * 64 + (((ks * 4 + lg) ^ (d & 7)) << 3)];
      oacc[nd] = __builtin_amdgcn_mfma_f32_16x16x32_bf16(pf, vf, oacc[nd], 0, 0, 0);
    }
    __builtin_amdgcn_s_setprio(0);
  }
}

DEV void attn_epilogue(u16* __restrict__ ob, int b, int g, int h, int q0,
                       const f32x4* oacc, float lsum, int lr, int lg, int w) {
  lsum += __shfl_xor(lsum, 16, 64);
  lsum += __shfl_xor(lsum, 32, 64);
  float inv = 1.0f / lsum;
  float iv[4];
  #pragma unroll
  for (int r = 0; r < 4; r++) iv[r] = __shfl(inv, lg * 4 + r, 64);
  #pragma unroll
  for (int r = 0; r < 4; r++) {
    int orow = q0 + w * 16 + lg * 4 + r;
    size_t base = (size_t)(b * T_ + orow) * 2048 + (size_t)(g * 4 + h) * 128;
    #pragma unroll
    for (int nd = 0; nd < 8; nd++)
      ob[base + nd * 16 + lr] = f2bf(oacc[nd][r] * iv[r]);
  }
}

// ---------- causal flash attention, Q norm+rope inlined ----------
// R14/R16 proven structure: counted vmcnt(8) pipeline, 1D grid 512, bid&7 = (b,g) ->
// XCD-local K/V; {31-p, p} pairing -> uniform 34 iters, 2 blocks/CU co-resident.
__global__ __launch_bounds__(256) void k_attn(
    const u16* __restrict__ qkvf, const float* __restrict__ gq,
    const float2* __restrict__ rope, const u16* __restrict__ kb,
    const u16* __restrict__ vtb, u16* __restrict__ ob) {
  __shared__ __align__(16) u16 Ks[2][64 * 128];
  __shared__ __align__(16) u16 Vs[2][128 * 64];
  __shared__ __align__(16) u16 Ps[4][16 * PROW];
  const int bid = blockIdx.x;          // 0..511
  const int hg = bid & 7;              // (b,g): b = hg>>2, g = hg&3
  const int rest = bid >> 3;           // 0..63
  const int hh = rest & 3;             // head within group
  const int p = rest >> 2;             // 0..15
  const int b = hg >> 2, g = hg & 3, h = hh;
  const int tid = threadIdx.x;
  const int w = tid >> 6, lane = tid & 63;
  const int lr = lane & 15, lg = lane >> 4;
  const u16* kh = kb + (size_t)hg * (T_ * 128);
  const u16* vh = vtb + (size_t)hg * (128 * T_);
  const float* gqh = gq + (size_t)(g * 4 + h) * 128;

  #pragma unroll 1
  for (int half = 0; half < 2; ++half) {
    const int qblk = half ? p : 31 - p;     // big tile first
    const int q0 = qblk * 64;
    // ---- inline Q: load from qkvf, RMSNorm * gq, RoPE, * QSC -> fragments
    bf16x8 qf[4];
    {
      const int qrow = q0 + w * 16 + lr;
      const u16* qsrc = qkvf + (size_t)(b * T_ + qrow) * 3072 + (size_t)(g * 4 + h) * 128;
      float qe[4][8];
      float ss = 0.f;
      #pragma unroll
      for (int kk = 0; kk < 4; kk++) {
        u16x8 raw = *(const u16x8*)&qsrc[kk * 32 + lg * 8];
        #pragma unroll
        for (int j = 0; j < 8; j++) {
          float v = bf2f(raw[j]);
          qe[kk][j] = v;
          ss += v * v;
        }
      }
      ss += __shfl_xor(ss, 16, 64);
      ss += __shfl_xor(ss, 32, 64);
      float inv = 1.0f / sqrtf(ss * (1.0f / 128.0f) + 1e-6f);
      #pragma unroll
      for (int kk = 0; kk < 2; kk++) {
        const float2* tp = &rope[(size_t)qrow * 64 + kk * 32 + lg * 8];
        u16x8 lo, hi;
        #pragma unroll
        for (int j = 0; j < 8; j++) {
          int d = kk * 32 + lg * 8 + j;
          float v0 = qe[kk][j] * inv * gqh[d];
          float v1 = qe[kk + 2][j] * inv * gqh[d + 64];
          float2 cs = tp[j];
          lo[j] = f2bf((v0 * cs.x - v1 * cs.y) * QSC);
          hi[j] = f2bf((v0 * cs.y + v1 * cs.x) * QSC);
        }
        qf[kk] = __builtin_bit_cast(bf16x8, lo);
        qf[kk + 2] = __builtin_bit_cast(bf16x8, hi);
      }
    }

    f32x4 oacc[8] = {};
    float lsum = 0.f;

    stage_tiles(kh, vh, 0, Ks[0], Vs[0], tid);
    int cur = 0;
    for (int jt = 0; jt <= qblk; ++jt) {
      // issue next tile's loads, then wait only for the CURRENT tile's (counted vmcnt)
      if (jt < qblk) {
        stage_tiles(kh, vh, (jt + 1) * 64, Ks[cur ^ 1], Vs[cur ^ 1], tid);
        asm volatile("s_waitcnt vmcnt(8)" ::: "memory");
      } else {
        asm volatile("s_waitcnt vmcnt(0)" ::: "memory");
      }
      barrier_mem();                      // B1: buf[cur] staged for all waves
      attn_tile(Ks[cur], Vs[cur], Ps[w], qf, oacc, lsum, lr, lg, w, jt == qblk);
      barrier_mem();                      // B2: all waves done reading buf[cur]
      cur ^= 1;                           //     (next iter's stage overwrites it)
    }
    attn_epilogue(ob, b, g, h, q0, oacc, lsum, lr, lg, w);
  }
}

// ---------- workspace layout (bytes) ----------
#define OFF_XB    ((size_t)0)          /* 16MB  x bf16 */
#define OFF_WQKVT ((size_t)16777216)   /* 12.6MB  [3072][2048] */
#define OFF_WOT   ((size_t)29360128)   /*  8MB */
#define OFF_ROPE  ((size_t)37748736)   /*  1MB */
#define OFF_OB    ((size_t)38797312)   /* 16MB  attn output */
#define OFF_KB    ((size_t)55574528)   /*  4MB */
#define OFF_VTB   ((size_t)59768832)   /*  4MB */
#define OFF_QKVF  ((size_t)63963136)   /* 25.2MB  [4096][3072] — stays live through attn */

extern "C" void kernel_launch(void* const* d_in, const int* in_sizes, int n_in,
                              void* d_out, int out_size, void* d_ws, size_t ws_size,
                              hipStream_t stream) {
  const float* x  = (const float*)d_in[0];
  const float* wq = (const float*)d_in[1];
  const float* wk = (const float*)d_in[2];
  const float* wv = (const float*)d_in[3];
  const float* wo = (const float*)d_in[4];
  const float* gq = (const float*)d_in[5];
  const float* gk = (const float*)d_in[6];
  float* out = (float*)d_out;
  char* ws = (char*)d_ws;

  u16*    xb    = (u16*)(ws + OFF_XB);
  u16*    wqkvt = (u16*)(ws + OFF_WQKVT);
  u16*    wot   = (u16*)(ws + OFF_WOT);
  float2* rope  = (float2*)(ws + OFF_ROPE);
  u16*    obuf  = (u16*)(ws + OFF_OB);
  u16*    kbuf  = (u16*)(ws + OFF_KB);
  u16*    vtb   = (u16*)(ws + OFF_VTB);
  u16*    qkvf  = (u16*)(ws + OFF_QKVF);

  // 1. fused prep: x convert + weight transposes + rope table
  k_prep<<<18944, 256, 0, stream>>>(x, wq, wk, wv, wo, xb, wqkvt, wot, rope);
  // 2. fused QKV projection: [4096][3072]
  k_gemm<u16><<<dim3(24, 32), 256, 0, stream>>>(xb, wqkvt, qkvf, MROWS, 3072, 2048);
  // 3. K norm+rope and V transpose pack (fused); Q handled inline in attention
  k_postgemm<<<5120, 256, 0, stream>>>(qkvf, gk, rope, kbuf, vtb);
  // 4. attention: R16 structure + padded P strip (conflict fix)
  k_attn<<<512, 256, 0, stream>>>(qkvf, gq, rope, kbuf, vtb, obuf);
  // 5. output projection (fp32 out)
  k_gemm<float><<<dim3(16, 32), 256, 0, stream>>>(obuf, wot, out, MROWS, 2048, 2048);
}

// Round 18
// 191.534 us; speedup vs baseline: 1.0595x; 1.0595x over previous
//
#include <hip/hip_runtime.h>
#include <cstdint>

typedef unsigned short u16;
typedef __attribute__((ext_vector_type(8))) __bf16 bf16x8;
typedef __attribute__((ext_vector_type(4))) float f32x4;
typedef __attribute__((ext_vector_type(16))) float f32x16;
typedef __attribute__((ext_vector_type(8))) unsigned short u16x8;

#define DEV __device__ __forceinline__

DEV u16 f2bf(float f) {
  __bf16 b = (__bf16)f;
  return __builtin_bit_cast(u16, b);
}
DEV float bf2f(u16 h) { return __uint_as_float(((unsigned)h) << 16); }
DEV float exp2_fast(float x) { float r; asm("v_exp_f32 %0, %1" : "=v"(r) : "v"(x)); return r; }
DEV void barrier_mem() { asm volatile("s_barrier" ::: "memory"); }

typedef __attribute__((address_space(1))) void gvoid_t;
typedef __attribute__((address_space(3))) void lvoid_t;

DEV void gload_lds16(const void* g, void* l) {
  __builtin_amdgcn_global_load_lds((gvoid_t*)(void*)(uintptr_t)g,
                                   (lvoid_t*)l, 16, 0, 0);
}

// ---- problem sizes
#define B_   2
#define T_   2048
#define DM   2048
#define MROWS (B_*T_)   // 4096
#define QSC  0.1275174f  // 128^-0.5 * log2(e): both attention mult factors + exp2 domain

// ---------- fused prep: x->bf16 convert + 4 weight transposes + rope table ----------
__global__ void k_prep(const float* __restrict__ x,
                       const float* __restrict__ wq, const float* __restrict__ wk,
                       const float* __restrict__ wv, const float* __restrict__ wo,
                       u16* __restrict__ xb, u16* __restrict__ wqkvt,
                       u16* __restrict__ wot, float2* __restrict__ rope) {
  const int bid = blockIdx.x;
  const int tid = threadIdx.x;
  if (bid < 8192) {                        // x f32 -> bf16 (float4 per thread)
    int i = bid * 256 + tid;
    float4 v = ((const float4*)x)[i];
    ((ushort4*)xb)[i] = make_ushort4(f2bf(v.x), f2bf(v.y), f2bf(v.z), f2bf(v.w));
    return;
  }
  if (bid >= 18432) {                      // rope table [t][64] (cos, sin)
    int i = (bid - 18432) * 256 + tid;
    int pos = i >> 6, d = i & 63;
    float ang = powf(10000.0f, -(float)d / 64.0f);
    float s, c;
    sincosf((float)pos * ang, &s, &c);
    rope[i] = make_float2(c, s);
    return;
  }
  __shared__ float tile[32][33];
  const int tb = bid - 8192;
  const float* in;
  u16* out;
  int C, bx, by, crow0;
  if (tb < 4096)      { in = wq; out = wqkvt; C = 2048; bx = tb & 63;          by = tb >> 6;          crow0 = 0; }
  else if (tb < 5120) { in = wk; out = wqkvt; C = 512;  bx = (tb - 4096) & 15; by = (tb - 4096) >> 4; crow0 = 2048; }
  else if (tb < 6144) { in = wv; out = wqkvt; C = 512;  bx = (tb - 5120) & 15; by = (tb - 5120) >> 4; crow0 = 2560; }
  else                { in = wo; out = wot;   C = 2048; bx = (tb - 6144) & 63; by = (tb - 6144) >> 6; crow0 = 0; }
  const int c0 = bx * 32, r0 = by * 32;
  const int tx = tid & 31, ty = tid >> 5;   // (32, 8)
  #pragma unroll
  for (int j = 0; j < 32; j += 8)
    tile[ty + j][tx] = in[(size_t)(r0 + ty + j) * C + c0 + tx];
  __syncthreads();
  #pragma unroll
  for (int j = 0; j < 32; j += 8)
    out[(size_t)(crow0 + c0 + ty + j) * 2048 + r0 + tx] = f2bf(tile[tx][ty + j]);
}

// ---------- bf16 GEMM: C[M][N] = A[M][K] * BT[N][K]^T ----------
// 128^2 tile, XCD swizzle; v_mfma_f32_32x32x16_bf16 inner (verified in r14).
template <typename OutT>
__global__ __launch_bounds__(256) void k_gemm(
    const u16* __restrict__ A, const u16* __restrict__ BT, OutT* __restrict__ C,
    int M, int N, int K) {
  __shared__ u16 As[128 * 64];
  __shared__ u16 Bs[128 * 64];
  const int tid = threadIdx.x;
  const int w = tid >> 6, lane = tid & 63;
  const int lr32 = lane & 31, l5 = lane >> 5;
  const int nx = gridDim.x;
  const int flat = blockIdx.y * nx + blockIdx.x;
  const int cpx = (nx * gridDim.y) >> 3;
  const int f = (flat & 7) * cpx + (flat >> 3);
  const int m0 = (f / nx) * 128, n0 = (f % nx) * 128;
  const int wr = w >> 1, wc = w & 1;
  f32x16 acc[2][2] = {};
  for (int k0 = 0; k0 < K; k0 += 64) {
    __syncthreads();
    #pragma unroll
    for (int i = 0; i < 4; i++) {
      int idx = i * 256 + tid;            // 0..1023
      int row = idx >> 3, blk = idx & 7;  // 8x16B blocks per 128B row
      int scol = ((blk ^ (row & 7)) << 3);
      gload_lds16(&A[(size_t)(m0 + row) * K + k0 + scol], &As[(idx & ~63) * 8]);
      gload_lds16(&BT[(size_t)(n0 + row) * K + k0 + scol], &Bs[(idx & ~63) * 8]);
    }
    __syncthreads();
    #pragma unroll
    for (int kc = 0; kc < 4; kc++) {      // K chunks of 16
      bf16x8 af[2], bfr[2];
      #pragma unroll
      for (int m = 0; m < 2; m++) {
        int row = wr * 64 + m * 32 + lr32;
        int blk = (kc * 2 + l5) ^ (row & 7);
        af[m] = *(const bf16x8*)&As[row * 64 + (blk << 3)];
      }
      #pragma unroll
      for (int n = 0; n < 2; n++) {
        int row = wc * 64 + n * 32 + lr32;
        int blk = (kc * 2 + l5) ^ (row & 7);
        bfr[n] = *(const bf16x8*)&Bs[row * 64 + (blk << 3)];
      }
      #pragma unroll
      for (int m = 0; m < 2; m++)
        #pragma unroll
        for (int n = 0; n < 2; n++)
          acc[m][n] = __builtin_amdgcn_mfma_f32_32x32x16_bf16(af[m], bfr[n], acc[m][n], 0, 0, 0);
    }
  }
  #pragma unroll
  for (int m = 0; m < 2; m++)
    #pragma unroll
    for (int n = 0; n < 2; n++)
      #pragma unroll
      for (int reg = 0; reg < 16; reg++) {
        int row = m0 + wr * 64 + m * 32 + (reg & 3) + 8 * (reg >> 2) + 4 * l5;
        int col = n0 + wc * 64 + n * 32 + lr32;
        if constexpr (sizeof(OutT) == 2) C[(size_t)row * N + col] = f2bf(acc[m][n][reg]);
        else                             C[(size_t)row * N + col] = acc[m][n][reg];
      }
}

// ---------- fused post-GEMM: K norm+rope ([0,4096) blocks) + V transpose pack ----------
__global__ void k_postgemm(const u16* __restrict__ qkvf, const float* __restrict__ gk,
                           const float2* __restrict__ tab, u16* __restrict__ kb,
                           u16* __restrict__ vt) {
  const int bid = blockIdx.x;
  const int w = threadIdx.x >> 6, lane = threadIdx.x & 63;
  if (bid < 4096) {                       // K: RMSNorm * gk, RoPE -> [b,g,t,d]
    int W = bid * 4 + w;                  // 0..16383
    int g = W & 3;
    int bt = W >> 2;
    int t = bt & 2047, b = bt >> 11;
    const u16* row = qkvf + (size_t)bt * 3072 + 2048 + (size_t)g * 128;
    float v0 = bf2f(row[lane]);
    float v1 = bf2f(row[lane + 64]);
    float ss = v0 * v0 + v1 * v1;
    #pragma unroll
    for (int off = 1; off < 64; off <<= 1) ss += __shfl_xor(ss, off, 64);
    float inv = 1.0f / sqrtf(ss * (1.0f / 128.0f) + 1e-6f);
    v0 *= inv * gk[g * 128 + lane];
    v1 *= inv * gk[g * 128 + 64 + lane];
    float2 cs = tab[t * 64 + lane];
    float o0 = v0 * cs.x - v1 * cs.y;
    float o1 = v0 * cs.y + v1 * cs.x;
    u16* orow = kb + ((size_t)((b * 4 + g) * 2048 + t)) * 128;
    orow[lane] = f2bf(o0);
    orow[lane + 64] = f2bf(o1);
  } else {                                // V: cols 2560..3071 -> VT [b,g,d,t]
    int W = (bid - 4096) * 4 + w;         // 0..4095
    int t8 = W & 255, dh = (W >> 8) & 1, bg = W >> 9;
    int b = bg >> 2, g = bg & 3;
    int t0 = t8 * 8;
    int d = dh * 64 + lane;
    u16x8 pack;
    #pragma unroll
    for (int j = 0; j < 8; j++)
      pack[j] = qkvf[(size_t)(b * 2048 + t0 + j) * 3072 + 2560 + g * 128 + d];
    *(u16x8*)&vt[((size_t)(bg * 128 + d)) * 2048 + t0] = pack;
  }
}

// ---------- staging: K tile [64][128] + VT tile [128][64], pre-swizzled source ----------
// Exactly 8 VMEM instructions per wave (4 K + 4 V) -> vmcnt(8) = previous stage complete.
DEV void stage_tiles(const u16* kh, const u16* vh, int j0, u16* Kbuf, u16* Vbuf, int tid) {
  #pragma unroll
  for (int i = 0; i < 4; i++) {
    int idx = i * 256 + tid;
    int row = idx >> 4, blk = idx & 15;   // 16x16B blocks per 256B K row
    gload_lds16(&kh[(size_t)(j0 + row) * 128 + ((blk ^ (row & 7)) << 3)],
                &Kbuf[(idx & ~63) * 8]);
  }
  #pragma unroll
  for (int i = 0; i < 4; i++) {
    int idx = i * 256 + tid;
    int row = idx >> 3, blk = idx & 7;    // 8x16B blocks per 128B VT row
    gload_lds16(&vh[(size_t)row * T_ + j0 + ((blk ^ (row & 7)) << 3)],
                &Vbuf[(idx & ~63) * 8]);
  }
}

// ---------- one q-tile's QK^T + bias-free exp2 softmax + PV ----------
// P = exp2(s) raw: s <= 16.32 (RMS-normed q,k; D^-0.5*log2e folded into q) -> P <= 8.2e4.
DEV void attn_tile(const u16* __restrict__ Kc, const u16* __restrict__ Vc,
                   u16* __restrict__ Psw, const bf16x8* qf, f32x4* oacc,
                   float& lsum, int lr, int lg, int w, bool diag) {
  // S^T = K . Q^T : col = q (lr), row = kv (c*16 + lg*4 + r)
  f32x4 s[4] = {};
  __builtin_amdgcn_s_setprio(1);
  #pragma unroll
  for (int kk = 0; kk < 4; kk++) {
    #pragma unroll
    for (int c = 0; c < 4; c++) {
      const int kvr = c * 16 + lr;
      bf16x8 kf = *(const bf16x8*)&Kc[kvr * 128 + (((kk * 4 + lg) ^ (kvr & 7)) << 3)];
      s[c] = __builtin_amdgcn_mfma_f32_16x16x32_bf16(kf, qf[kk], s[c], 0, 0, 0);
    }
  }
  __builtin_amdgcn_s_setprio(0);
  if (diag) {
    #pragma unroll
    for (int c = 0; c < 4; c++)
      #pragma unroll
      for (int r = 0; r < 4; r++)
        if (c * 16 + lg * 4 + r > w * 16 + lr) s[c][r] = -1.0e30f;
  }
  float rs = 0.f;
  #pragma unroll
  for (int c = 0; c < 4; c++)
    #pragma unroll
    for (int r = 0; r < 4; r++) {
      float pv = exp2_fast(s[c][r]);
      s[c][r] = pv;
      rs += pv;
    }
  lsum += rs;                 // per-lane partial; cross-lane reduce deferred to epilogue
  // P store: P[q=lr][kv quad c*16+lg*4], b64, XOR-swizzled 8B blocks
  #pragma unroll
  for (int c = 0; c < 4; c++) {
    ushort4 q4 = make_ushort4(f2bf(s[c][0]), f2bf(s[c][1]), f2bf(s[c][2]), f2bf(s[c][3]));
    int blk8 = (c * 4 + lg) ^ ((lr & 7) << 1);
    *(ushort4*)&Psw[lr * 64 + blk8 * 4] = q4;
  }
  // O += P V
  #pragma unroll
  for (int ks = 0; ks < 2; ks++) {
    bf16x8 pf = *(const bf16x8*)&Psw[lr * 64 +
                 (((2 * (ks * 4 + lg)) ^ ((lr & 7) << 1)) << 2)];
    __builtin_amdgcn_s_setprio(1);
    #pragma unroll
    for (int nd = 0; nd < 8; nd++) {
      const int d = nd * 16 + lr;
      bf16x8 vf = *(const bf16x8*)&Vc[d * 64 + (((ks * 4 + lg) ^ (d & 7)) << 3)];
      oacc[nd] = __builtin_amdgcn_mfma_f32_16x16x32_bf16(pf, vf, oacc[nd], 0, 0, 0);
    }
    __builtin_amdgcn_s_setprio(0);
  }
}

DEV void attn_epilogue(u16* __restrict__ ob, int b, int g, int h, int q0,
                       const f32x4* oacc, float lsum, int lr, int lg, int w) {
  lsum += __shfl_xor(lsum, 16, 64);
  lsum += __shfl_xor(lsum, 32, 64);
  float inv = 1.0f / lsum;
  float iv[4];
  #pragma unroll
  for (int r = 0; r < 4; r++) iv[r] = __shfl(inv, lg * 4 + r, 64);
  #pragma unroll
  for (int r = 0; r < 4; r++) {
    int orow = q0 + w * 16 + lg * 4 + r;
    size_t base = (size_t)(b * T_ + orow) * 2048 + (size_t)(g * 4 + h) * 128;
    #pragma unroll
    for (int nd = 0; nd < 8; nd++)
      ob[base + nd * 16 + lr] = f2bf(oacc[nd][r] * iv[r]);
  }
}

// ---------- causal flash attention, Q norm+rope inlined ----------
// R14/R16 proven structure: counted vmcnt(8) pipeline, 1D grid 512, bid&7 = (b,g) ->
// XCD-local K/V; {31-p, p} pairing -> uniform 34 iters, 2 blocks/CU co-resident.
__global__ __launch_bounds__(256) void k_attn(
    const u16* __restrict__ qkvf, const float* __restrict__ gq,
    const float2* __restrict__ rope, const u16* __restrict__ kb,
    const u16* __restrict__ vtb, u16* __restrict__ ob) {
  __shared__ __align__(16) u16 Ks[2][64 * 128];
  __shared__ __align__(16) u16 Vs[2][128 * 64];
  __shared__ __align__(16) u16 Ps[4][16 * 64];
  const int bid = blockIdx.x;          // 0..511
  const int hg = bid & 7;              // (b,g): b = hg>>2, g = hg&3
  const int rest = bid >> 3;           // 0..63
  const int hh = rest & 3;             // head within group
  const int p = rest >> 2;             // 0..15
  const int b = hg >> 2, g = hg & 3, h = hh;
  const int tid = threadIdx.x;
  const int w = tid >> 6, lane = tid & 63;
  const int lr = lane & 15, lg = lane >> 4;
  const u16* kh = kb + (size_t)hg * (T_ * 128);
  const u16* vh = vtb + (size_t)hg * (128 * T_);
  const float* gqh = gq + (size_t)(g * 4 + h) * 128;

  #pragma unroll 1
  for (int half = 0; half < 2; ++half) {
    const int qblk = half ? p : 31 - p;     // big tile first
    const int q0 = qblk * 64;
    // ---- inline Q: load from qkvf, RMSNorm * gq, RoPE, * QSC -> fragments
    bf16x8 qf[4];
    {
      const int qrow = q0 + w * 16 + lr;
      const u16* qsrc = qkvf + (size_t)(b * T_ + qrow) * 3072 + (size_t)(g * 4 + h) * 128;
      float qe[4][8];
      float ss = 0.f;
      #pragma unroll
      for (int kk = 0; kk < 4; kk++) {
        u16x8 raw = *(const u16x8*)&qsrc[kk * 32 + lg * 8];
        #pragma unroll
        for (int j = 0; j < 8; j++) {
          float v = bf2f(raw[j]);
          qe[kk][j] = v;
          ss += v * v;
        }
      }
      ss += __shfl_xor(ss, 16, 64);
      ss += __shfl_xor(ss, 32, 64);
      float inv = 1.0f / sqrtf(ss * (1.0f / 128.0f) + 1e-6f);
      #pragma unroll
      for (int kk = 0; kk < 2; kk++) {
        const float2* tp = &rope[(size_t)qrow * 64 + kk * 32 + lg * 8];
        u16x8 lo, hi;
        #pragma unroll
        for (int j = 0; j < 8; j++) {
          int d = kk * 32 + lg * 8 + j;
          float v0 = qe[kk][j] * inv * gqh[d];
          float v1 = qe[kk + 2][j] * inv * gqh[d + 64];
          float2 cs = tp[j];
          lo[j] = f2bf((v0 * cs.x - v1 * cs.y) * QSC);
          hi[j] = f2bf((v0 * cs.y + v1 * cs.x) * QSC);
        }
        qf[kk] = __builtin_bit_cast(bf16x8, lo);
        qf[kk + 2] = __builtin_bit_cast(bf16x8, hi);
      }
    }

    f32x4 oacc[8] = {};
    float lsum = 0.f;

    stage_tiles(kh, vh, 0, Ks[0], Vs[0], tid);
    int cur = 0;
    for (int jt = 0; jt <= qblk; ++jt) {
      // issue next tile's loads, then wait only for the CURRENT tile's (counted vmcnt)
      if (jt < qblk) {
        stage_tiles(kh, vh, (jt + 1) * 64, Ks[cur ^ 1], Vs[cur ^ 1], tid);
        asm volatile("s_waitcnt vmcnt(8)" ::: "memory");
      } else {
        asm volatile("s_waitcnt vmcnt(0)" ::: "memory");
      }
      barrier_mem();                      // B1: buf[cur] staged for all waves
      attn_tile(Ks[cur], Vs[cur], Ps[w], qf, oacc, lsum, lr, lg, w, jt == qblk);
      barrier_mem();                      // B2: all waves done reading buf[cur]
      cur ^= 1;                           //     (next iter's stage overwrites it)
    }
    attn_epilogue(ob, b, g, h, q0, oacc, lsum, lr, lg, w);
  }
}

// ---------- workspace layout (bytes) ----------
#define OFF_XB    ((size_t)0)          /* 16MB  x bf16 */
#define OFF_WQKVT ((size_t)16777216)   /* 12.6MB  [3072][2048] */
#define OFF_WOT   ((size_t)29360128)   /*  8MB */
#define OFF_ROPE  ((size_t)37748736)   /*  1MB */
#define OFF_OB    ((size_t)38797312)   /* 16MB  attn output */
#define OFF_KB    ((size_t)55574528)   /*  4MB */
#define OFF_VTB   ((size_t)59768832)   /*  4MB */
#define OFF_QKVF  ((size_t)63963136)   /* 25.2MB  [4096][3072] — stays live through attn */

extern "C" void kernel_launch(void* const* d_in, const int* in_sizes, int n_in,
                              void* d_out, int out_size, void* d_ws, size_t ws_size,
                              hipStream_t stream) {
  const float* x  = (const float*)d_in[0];
  const float* wq = (const float*)d_in[1];
  const float* wk = (const float*)d_in[2];
  const float* wv = (const float*)d_in[3];
  const float* wo = (const float*)d_in[4];
  const float* gq = (const float*)d_in[5];
  const float* gk = (const float*)d_in[6];
  float* out = (float*)d_out;
  char* ws = (char*)d_ws;

  u16*    xb    = (u16*)(ws + OFF_XB);
  u16*    wqkvt = (u16*)(ws + OFF_WQKVT);
  u16*    wot   = (u16*)(ws + OFF_WOT);
  float2* rope  = (float2*)(ws + OFF_ROPE);
  u16*    obuf  = (u16*)(ws + OFF_OB);
  u16*    kbuf  = (u16*)(ws + OFF_KB);
  u16*    vtb   = (u16*)(ws + OFF_VTB);
  u16*    qkvf  = (u16*)(ws + OFF_QKVF);

  // 1. fused prep: x convert + weight transposes + rope table
  k_prep<<<18944, 256, 0, stream>>>(x, wq, wk, wv, wo, xb, wqkvt, wot, rope);
  // 2. fused QKV projection: [4096][3072]
  k_gemm<u16><<<dim3(24, 32), 256, 0, stream>>>(xb, wqkvt, qkvf, MROWS, 3072, 2048);
  // 3. K norm+rope and V transpose pack (fused); Q handled inline in attention
  k_postgemm<<<5120, 256, 0, stream>>>(qkvf, gk, rope, kbuf, vtb);
  // 4. attention: R16 structure (counted vmcnt(8), XCD-local, uniform 34 iters)
  k_attn<<<512, 256, 0, stream>>>(qkvf, gq, rope, kbuf, vtb, obuf);
  // 5. output projection (fp32 out)
  k_gemm<float><<<dim3(16, 32), 256, 0, stream>>>(obuf, wot, out, MROWS, 2048, 2048);
}